// Round 4
// baseline (252.063 us; speedup 1.0000x reference)
//
#include <hip/hip_runtime.h>

#define N 1024
#define NN (N * N)
#define STRIPS 19          // 18*56 + 16 = 1024 valid cols
#define SEGS 16            // 16 * 64 = 1024 rows
#define SEGROWS 64
#define NWAVES (STRIPS * SEGS * 8)   // 2432 blocks (1 wave each)

__device__ __forceinline__ int refl(int i) {   // reflect-101; any i in [-(N-1), 2N-2]
    if (i < 0) return -i;
    if (i >= N) return 2 * N - 2 - i;
    return i;
}

__global__ __launch_bounds__(64)
void edge_diff_kernel(const float* __restrict__ op, const float* __restrict__ gt,
                      unsigned int* __restrict__ partials)
{
    const float w0 = 0.05448868f, w1 = 0.24420134f, w2 = 0.40261996f,
                w3 = 0.24420134f, w4 = 0.05448868f;

    int b = blockIdx.x;
    int img   = b / (STRIPS * SEGS);
    int rem   = b - img * (STRIPS * SEGS);
    int strip = rem / SEGS;
    int seg   = rem - strip * SEGS;
    int lane  = threadIdx.x;                 // 0..63

    int cb = strip * 56 - 4;
    int c  = cb + lane;                      // this lane's global column
    int cR = refl(c < 0 ? c : (c >= N ? c : c));   // refl handles both ends
    cR = refl(c);

    const float* A = op + (size_t)img * 3 * NN;
    const float* B = gt + (size_t)img * 3 * NN;

    const bool cz0 = (c == 0), czN = (c == N - 1);
    const bool valid = (lane >= 4) && (lane <= 59) && (c >= 0) && (c < N);

    const int iL1 = lane - 1, iL2 = lane - 2, iR1 = lane + 1, iR2 = lane + 2;

    // rolling windows, image A
    float ha0=0,ha1=0,ha2=0,ha3=0,ha4=0;         // h-blurred gray rows y-4..y
    float bla0=0,bla1=0,bla2=0;                  // blurred rows y-4..y-2
    float mga0=0,mga1=0,mga2=0;                  // mag rows w-1,w,w+1  (w=y-4)
    float mgla0=0,mgla1=0,mgla2=0;               // mag shifted left  (col c-1)
    float mgra0=0,mgra1=0,mgra2=0;               // mag shifted right (col c+1)
    int   axa = 0;                               // axis code of row w (delayed 1 step)
    // image B
    float hb0=0,hb1=0,hb2=0,hb3=0,hb4=0;
    float blb0=0,blb1=0,blb2=0;
    float mgb0=0,mgb1=0,mgb2=0;
    float mglb0=0,mglb1=0,mglb2=0;
    float mgrb0=0,mgrb1=0,mgrb2=0;
    int   axb = 0;

    int acc = 0;
    const int R0 = seg * SEGROWS;

    for (int y = R0 - 4; y <= R0 + 67; ++y) {
        int rr = refl(y);
        const float* pa = A + (size_t)rr * N + cR;
        const float* pb = B + (size_t)rr * N + cR;

        // gray (reflect-padded rows AND cols via reflected load index)
        float ga = 0.299f * pa[0] + 0.587f * pa[NN] + 0.114f * pa[2 * NN];
        float gb = 0.299f * pb[0] + 0.587f * pb[NN] + 0.114f * pb[2 * NN];

        // horizontal blur via cross-lane shuffles
        float gal2 = __shfl(ga, iL2, 64), gal1 = __shfl(ga, iL1, 64);
        float gar1 = __shfl(ga, iR1, 64), gar2 = __shfl(ga, iR2, 64);
        float gbl2 = __shfl(gb, iL2, 64), gbl1 = __shfl(gb, iL1, 64);
        float gbr1 = __shfl(gb, iR1, 64), gbr2 = __shfl(gb, iR2, 64);
        float hna = w0*gal2 + w1*gal1 + w2*ga + w3*gar1 + w4*gar2;
        float hnb = w0*gbl2 + w1*gbl1 + w2*gb + w3*gbr1 + w4*gbr2;
        ha0=ha1; ha1=ha2; ha2=ha3; ha3=ha4; ha4=hna;
        hb0=hb1; hb1=hb2; hb2=hb3; hb3=hb4; hb4=hnb;

        // vertical blur -> blurred row y-2
        float bna = w0*ha0 + w1*ha1 + w2*ha2 + w3*ha3 + w4*ha4;
        float bnb = w0*hb0 + w1*hb1 + w2*hb2 + w3*hb3 + w4*hb4;
        bla0=bla1; bla1=bla2; bla2=bna;
        blb0=blb1; blb1=blb2; blb2=bnb;

        // Sobel + magnitude + axis at row z = y-3 (edge-clamp rows/cols)
        int z = y - 3;
        float Ara = (z == 0)     ? bla1 : bla0;
        float Cra = (z == N - 1) ? bla1 : bla2;
        float Arb = (z == 0)     ? blb1 : blb0;
        float Crb = (z == N - 1) ? blb1 : blb2;

        float sa = Ara + 2.f*bla1 + Cra;  float da = Cra - Ara;
        float sb = Arb + 2.f*blb1 + Crb;  float db = Crb - Arb;

        float sal = __shfl(sa, iL1, 64), sar = __shfl(sa, iR1, 64);
        float dal = __shfl(da, iL1, 64), dar = __shfl(da, iR1, 64);
        float sbl = __shfl(sb, iL1, 64), sbr = __shfl(sb, iR1, 64);
        float dbl = __shfl(db, iL1, 64), dbr = __shfl(db, iR1, 64);
        sal = cz0 ? sa : sal;  dal = cz0 ? da : dal;
        sar = czN ? sa : sar;  dar = czN ? da : dar;
        sbl = cz0 ? sb : sbl;  dbl = cz0 ? db : dbl;
        sbr = czN ? sb : sbr;  dbr = czN ? db : dbr;

        float gxa = sar - sal;            float gya = dal + 2.f*da + dar;
        float gxb = sbr - sbl;            float gyb = dbl + 2.f*db + dbr;
        float maga = sqrtf(gxa*gxa + gya*gya + 1e-6f);
        float magb = sqrtf(gxb*gxb + gyb*gyb + 1e-6f);

        float axx = fabsf(gxa), ayy = fabsf(gya);
        int cda = (ayy <= 0.41421356f * axx) ? 0
                : (ayy >= 2.41421356f * axx) ? 1
                : (((gxa > 0.f) == (gya > 0.f)) ? 2 : 3);
        float bxx = fabsf(gxb), byy = fabsf(gyb);
        int cdb = (byy <= 0.41421356f * bxx) ? 0
                : (byy >= 2.41421356f * bxx) ? 1
                : (((gxb > 0.f) == (gyb > 0.f)) ? 2 : 3);

        float mala = __shfl(maga, iL1, 64); mala = cz0 ? 0.f : mala;
        float mara = __shfl(maga, iR1, 64); mara = czN ? 0.f : mara;
        float malb = __shfl(magb, iL1, 64); malb = cz0 ? 0.f : malb;
        float marb = __shfl(magb, iR1, 64); marb = czN ? 0.f : marb;

        mga0=mga1;   mga1=mga2;   mga2=maga;
        mgla0=mgla1; mgla1=mgla2; mgla2=mala;
        mgra0=mgra1; mgra1=mgra2; mgra2=mara;
        mgb0=mgb1;   mgb1=mgb2;   mgb2=magb;
        mglb0=mglb1; mglb1=mglb2; mglb2=malb;
        mgrb0=mgrb1; mgrb1=mgrb2; mgrb2=marb;

        int axUa = axa; axa = cda;     // axis of row w was computed last step
        int axUb = axb; axb = cdb;

        // NMS + threshold at row w = y-4
        if (y >= R0 + 4) {
            int w = y - 4;
            float m0a = mga0, l0a = mgla0, r0a = mgra0;
            float m2a = mga2, l2a = mgla2, r2a = mgra2;
            float m0b = mgb0, l0b = mglb0, r0b = mgrb0;
            float m2b = mgb2, l2b = mglb2, r2b = mgrb2;
            if (w == 0)     { m0a=0; l0a=0; r0a=0; m0b=0; l0b=0; r0b=0; }
            if (w == N - 1) { m2a=0; l2a=0; r2a=0; m2b=0; l2b=0; r2b=0; }

            float n1a = (axUa == 0) ? mgra1 : (axUa == 1) ? m0a : (axUa == 2) ? r0a : l0a;
            float n2a = (axUa == 0) ? mgla1 : (axUa == 1) ? m2a : (axUa == 2) ? l2a : r2a;
            float n1b = (axUb == 0) ? mgrb1 : (axUb == 1) ? m0b : (axUb == 2) ? r0b : l0b;
            float n2b = (axUb == 0) ? mglb1 : (axUb == 1) ? m2b : (axUb == 2) ? l2b : r2b;

            bool ea = (mga1 > n1a) && (mga1 > n2a) && (mga1 > 0.1f);
            bool eb = (mgb1 > n1b) && (mgb1 > n2b) && (mgb1 > 0.1f);
            acc += (int)(valid && (ea != eb));
        }
    }

    for (int off = 32; off > 0; off >>= 1)
        acc += __shfl_down(acc, off, 64);
    if (lane == 0)
        partials[b] = (unsigned int)acc;
}

__global__ __launch_bounds__(256)
void finalize_kernel(const unsigned int* __restrict__ partials, float* __restrict__ out)
{
    __shared__ unsigned int ws[4];
    int tid = threadIdx.x;
    unsigned int sum = 0;
    for (int i = tid; i < NWAVES; i += 256)
        sum += partials[i];
    int d = (int)sum;
    for (int off = 32; off > 0; off >>= 1)
        d += __shfl_down(d, off, 64);
    if ((tid & 63) == 0) ws[tid >> 6] = (unsigned int)d;
    __syncthreads();
    if (tid == 0)
        out[0] = (float)(ws[0] + ws[1] + ws[2] + ws[3]) / 8388608.0f;  // 8*1024*1024
}

extern "C" void kernel_launch(void* const* d_in, const int* in_sizes, int n_in,
                              void* d_out, int out_size, void* d_ws, size_t ws_size,
                              hipStream_t stream)
{
    const float* op = (const float*)d_in[0];
    const float* gt = (const float*)d_in[1];
    unsigned int* partials = (unsigned int*)d_ws;   // NWAVES uints, fully overwritten

    edge_diff_kernel<<<dim3(NWAVES), dim3(64), 0, stream>>>(op, gt, partials);
    finalize_kernel<<<1, dim3(256), 0, stream>>>(partials, (float*)d_out);
}

// Round 5
// 232.925 us; speedup vs baseline: 1.0822x; 1.0822x over previous
//
#include <hip/hip_runtime.h>

#define N 1024
#define NN (N * N)
#define STRIPS 19          // 18*56 + 16 = 1024 valid cols
#define SEGS 32            // 32 * 32 = 1024 rows
#define SEGROWS 32
#define NWAVES (STRIPS * SEGS * 8)   // 4864 waves (1 per block)

__device__ __forceinline__ int refl(int i) {   // reflect-101
    if (i < 0) return -i;
    if (i >= N) return 2 * N - 2 - i;
    return i;
}

__global__ __launch_bounds__(64)
void edge_diff_kernel(const float* __restrict__ op, const float* __restrict__ gt,
                      unsigned int* __restrict__ partials)
{
    const float w0 = 0.05448868f, w1 = 0.24420134f, w2 = 0.40261996f,
                w3 = 0.24420134f, w4 = 0.05448868f;

    int b = blockIdx.x;
    int img   = b / (STRIPS * SEGS);
    int rem   = b - img * (STRIPS * SEGS);
    int strip = rem / SEGS;
    int seg   = rem - strip * SEGS;
    int lane  = threadIdx.x;                 // 0..63

    int cb = strip * 56 - 4;
    int c  = cb + lane;                      // this lane's global column
    int cR = refl(c);

    const float* A = op + (size_t)img * 3 * NN;
    const float* B = gt + (size_t)img * 3 * NN;

    const bool cz0 = (c == 0), czN = (c == N - 1);
    const bool valid = (lane >= 4) && (lane <= 59) && (c >= 0) && (c < N);

    const int iL1 = lane - 1, iL2 = lane - 2, iR1 = lane + 1, iR2 = lane + 2;

    // rolling windows, image A
    float ha0=0,ha1=0,ha2=0,ha3=0,ha4=0;         // h-blurred gray rows y-4..y
    float bla0=0,bla1=0,bla2=0;                  // blurred rows y-4..y-2
    float mga0=0,mga1=0,mga2=0;                  // mag rows w-1,w,w+1  (w=y-4)
    float mgla0=0,mgla1=0,mgla2=0;               // mag col c-1
    float mgra0=0,mgra1=0,mgra2=0;               // mag col c+1
    int   axa = 0;
    // image B
    float hb0=0,hb1=0,hb2=0,hb3=0,hb4=0;
    float blb0=0,blb1=0,blb2=0;
    float mgb0=0,mgb1=0,mgb2=0;
    float mglb0=0,mglb1=0,mglb2=0;
    float mgrb0=0,mgrb1=0,mgrb2=0;
    int   axb = 0;

    int acc = 0;
    const int R0 = seg * SEGROWS;

#pragma unroll 4
    for (int y = R0 - 4; y <= R0 + 35; ++y) {    // 40 iterations
        int rr = refl(y);
        const float* pa = A + (size_t)rr * N + cR;
        const float* pb = B + (size_t)rr * N + cR;

        float ga = 0.299f * pa[0] + 0.587f * pa[NN] + 0.114f * pa[2 * NN];
        float gb = 0.299f * pb[0] + 0.587f * pb[NN] + 0.114f * pb[2 * NN];

        // horizontal blur via cross-lane shuffles
        float gal2 = __shfl(ga, iL2, 64), gal1 = __shfl(ga, iL1, 64);
        float gar1 = __shfl(ga, iR1, 64), gar2 = __shfl(ga, iR2, 64);
        float gbl2 = __shfl(gb, iL2, 64), gbl1 = __shfl(gb, iL1, 64);
        float gbr1 = __shfl(gb, iR1, 64), gbr2 = __shfl(gb, iR2, 64);
        float hna = w0*gal2 + w1*gal1 + w2*ga + w3*gar1 + w4*gar2;
        float hnb = w0*gbl2 + w1*gbl1 + w2*gb + w3*gbr1 + w4*gbr2;
        ha0=ha1; ha1=ha2; ha2=ha3; ha3=ha4; ha4=hna;
        hb0=hb1; hb1=hb2; hb2=hb3; hb3=hb4; hb4=hnb;

        // vertical blur -> blurred row y-2
        float bna = w0*ha0 + w1*ha1 + w2*ha2 + w3*ha3 + w4*ha4;
        float bnb = w0*hb0 + w1*hb1 + w2*hb2 + w3*hb3 + w4*hb4;
        bla0=bla1; bla1=bla2; bla2=bna;
        blb0=blb1; blb1=blb2; blb2=bnb;

        // Sobel + magnitude + axis at row z = y-3 (edge-clamp rows/cols)
        int z = y - 3;
        float Ara = (z == 0)     ? bla1 : bla0;
        float Cra = (z == N - 1) ? bla1 : bla2;
        float Arb = (z == 0)     ? blb1 : blb0;
        float Crb = (z == N - 1) ? blb1 : blb2;

        float sa = Ara + 2.f*bla1 + Cra;  float da = Cra - Ara;
        float sb = Arb + 2.f*blb1 + Crb;  float db = Crb - Arb;

        float sal = __shfl(sa, iL1, 64), sar = __shfl(sa, iR1, 64);
        float dal = __shfl(da, iL1, 64), dar = __shfl(da, iR1, 64);
        float sbl = __shfl(sb, iL1, 64), sbr = __shfl(sb, iR1, 64);
        float dbl = __shfl(db, iL1, 64), dbr = __shfl(db, iR1, 64);
        sal = cz0 ? sa : sal;  dal = cz0 ? da : dal;
        sar = czN ? sa : sar;  dar = czN ? da : dar;
        sbl = cz0 ? sb : sbl;  dbl = cz0 ? db : dbl;
        sbr = czN ? sb : sbr;  dbr = czN ? db : dbr;

        float gxa = sar - sal;            float gya = dal + 2.f*da + dar;
        float gxb = sbr - sbl;            float gyb = dbl + 2.f*db + dbr;
        float maga = sqrtf(gxa*gxa + gya*gya + 1e-6f);
        float magb = sqrtf(gxb*gxb + gyb*gyb + 1e-6f);

        float axx = fabsf(gxa), ayy = fabsf(gya);
        int cda = (ayy <= 0.41421356f * axx) ? 0
                : (ayy >= 2.41421356f * axx) ? 1
                : (((gxa > 0.f) == (gya > 0.f)) ? 2 : 3);
        float bxx = fabsf(gxb), byy = fabsf(gyb);
        int cdb = (byy <= 0.41421356f * bxx) ? 0
                : (byy >= 2.41421356f * bxx) ? 1
                : (((gxb > 0.f) == (gyb > 0.f)) ? 2 : 3);

        float mala = __shfl(maga, iL1, 64); mala = cz0 ? 0.f : mala;
        float mara = __shfl(maga, iR1, 64); mara = czN ? 0.f : mara;
        float malb = __shfl(magb, iL1, 64); malb = cz0 ? 0.f : malb;
        float marb = __shfl(magb, iR1, 64); marb = czN ? 0.f : marb;

        mga0=mga1;   mga1=mga2;   mga2=maga;
        mgla0=mgla1; mgla1=mgla2; mgla2=mala;
        mgra0=mgra1; mgra1=mgra2; mgra2=mara;
        mgb0=mgb1;   mgb1=mgb2;   mgb2=magb;
        mglb0=mglb1; mglb1=mglb2; mglb2=malb;
        mgrb0=mgrb1; mgrb1=mgrb2; mgrb2=marb;

        int axUa = axa; axa = cda;
        int axUb = axb; axb = cdb;

        // NMS + threshold at row w = y-4
        if (y >= R0 + 4) {
            int w = y - 4;
            float m0a = mga0, l0a = mgla0, r0a = mgra0;
            float m2a = mga2, l2a = mgla2, r2a = mgra2;
            float m0b = mgb0, l0b = mglb0, r0b = mgrb0;
            float m2b = mgb2, l2b = mglb2, r2b = mgrb2;
            if (w == 0)     { m0a=0; l0a=0; r0a=0; m0b=0; l0b=0; r0b=0; }
            if (w == N - 1) { m2a=0; l2a=0; r2a=0; m2b=0; l2b=0; r2b=0; }

            float n1a = (axUa == 0) ? mgra1 : (axUa == 1) ? m0a : (axUa == 2) ? r0a : l0a;
            float n2a = (axUa == 0) ? mgla1 : (axUa == 1) ? m2a : (axUa == 2) ? l2a : r2a;
            float n1b = (axUb == 0) ? mgrb1 : (axUb == 1) ? m0b : (axUb == 2) ? r0b : l0b;
            float n2b = (axUb == 0) ? mglb1 : (axUb == 1) ? m2b : (axUb == 2) ? l2b : r2b;

            bool ea = (mga1 > n1a) && (mga1 > n2a) && (mga1 > 0.1f);
            bool eb = (mgb1 > n1b) && (mgb1 > n2b) && (mgb1 > 0.1f);
            acc += (int)(valid && (ea != eb));
        }
    }

    for (int off = 32; off > 0; off >>= 1)
        acc += __shfl_down(acc, off, 64);
    if (lane == 0)
        partials[b] = (unsigned int)acc;
}

__global__ __launch_bounds__(256)
void finalize_kernel(const unsigned int* __restrict__ partials, float* __restrict__ out)
{
    __shared__ unsigned int ws[4];
    int tid = threadIdx.x;
    unsigned int sum = 0;
    for (int i = tid; i < NWAVES; i += 256)
        sum += partials[i];
    int d = (int)sum;
    for (int off = 32; off > 0; off >>= 1)
        d += __shfl_down(d, off, 64);
    if ((tid & 63) == 0) ws[tid >> 6] = (unsigned int)d;
    __syncthreads();
    if (tid == 0)
        out[0] = (float)(ws[0] + ws[1] + ws[2] + ws[3]) / 8388608.0f;  // 8*1024*1024
}

extern "C" void kernel_launch(void* const* d_in, const int* in_sizes, int n_in,
                              void* d_out, int out_size, void* d_ws, size_t ws_size,
                              hipStream_t stream)
{
    const float* op = (const float*)d_in[0];
    const float* gt = (const float*)d_in[1];
    unsigned int* partials = (unsigned int*)d_ws;   // NWAVES uints, fully overwritten

    edge_diff_kernel<<<dim3(NWAVES), dim3(64), 0, stream>>>(op, gt, partials);
    finalize_kernel<<<1, dim3(256), 0, stream>>>(partials, (float*)d_out);
}